// Round 1
// baseline (201.475 us; speedup 1.0000x reference)
//
#include <hip/hip_runtime.h>

#define HH 28
#define WW 28
#define NPIX 784          // 28*28
#define BLOCK 832         // 13 waves; threads 784..831 idle on compute
#define PSTRIDE 40        // padded row stride in float4 slots (≡ 0 mod 8)
#define PROWS 36          // rows -4..31 (halo 4 covers |jitter|<=2 + taps ±2)
#define PSLOTS (PROWS * PSTRIDE)   // 1440 slots = 23040 B

// LDS-conflict-free gather:
//  - image staged into a zero-padded 36x40 float4 tile (4 images interleaved);
//    OOB taps read exact 0.0 == reference's in_b mask, so no clamping and every
//    tap is ds_read_b128 [one base VGPR + compile-time immediate].
//  - lanes are PERMUTED so that any 16 consecutive lanes have base slots with
//    distinct residues mod 16 (bucket by slot(ce)%16, round-robin emit).
//    Taps add a wave-uniform immediate, so all 25 gathers stay conflict-free.
//  - results un-permuted through a double-buffered LDS result tile, stored
//    coalesced one iteration later (in the long compute window, so the
//    barrier's vmcnt drain is cheap).
__global__ __launch_bounds__(BLOCK, 7) void axs_89807766159734_kernel(
    const float* __restrict__ x, const float* __restrict__ pos2d,
    const float* __restrict__ weight, float* __restrict__ out,
    int nGroups)
{
    __shared__ float4 img[PSLOTS];          // 23040 B, zero halo
    __shared__ float4 resA[NPIX];           // 12544 B
    __shared__ float4 resB[NPIX];           // 12544 B
    __shared__ unsigned short ordered[NPIX];
    __shared__ unsigned short ovf[NPIX];
    __shared__ int cnt[16];
    __shared__ int ovfn;

    const int tid = threadIdx.x;
    const bool act = tid < NPIX;

    // ---- one-time setup: zero halo, build residue-round-robin permutation ----
    for (int s = tid; s < PSLOTS; s += BLOCK) img[s] = make_float4(0.f, 0.f, 0.f, 0.f);
    if (act) ordered[tid] = 0xFFFFu;
    if (tid < 16) cnt[tid] = 0;
    if (tid == 0) ovfn = 0;
    __syncthreads();

    int K16 = 0, rank = 0;
    if (act) {
        const float p0 = pos2d[2 * tid], p1 = pos2d[2 * tid + 1];
        const int c0 = (int)rintf(p0), c1 = (int)rintf(p1);
        const int a0 = min(max(c0, -2), HH + 1);   // clamp for addressing only
        const int a1 = min(max(c1, -2), WW + 1);
        K16 = ((a0 + 2) * PSTRIDE + (a1 + 2)) & 15;   // base-slot residue mod 16
        rank = atomicAdd(&cnt[K16], 1);
    }
    __syncthreads();
    if (act) {
        const int L = rank * 16 + K16;      // lane that should own this pixel
        if (L < NPIX) ordered[L] = (unsigned short)tid;
        else          ovf[atomicAdd(&ovfn, 1)] = (unsigned short)tid;
    }
    __syncthreads();
    if (act && ordered[tid] == 0xFFFFu) {   // fill holes from overflow pool
        const int o = atomicAdd(&ovfn, -1) - 1;
        ordered[tid] = ovf[o];
    }
    __syncthreads();

    // ---- per-thread tap table for the ASSIGNED pixel (separable, 25 regs) ----
    int ap = tid;
    int base = 0;
    float coef[5][5];
    if (act) {
        ap = ordered[tid];
        const float p0 = pos2d[2 * ap], p1 = pos2d[2 * ap + 1];
        const float sw = fmaxf(weight[ap], 0.f);          // relu(weight)
        const float r0f = rintf(p0), r1f = rintf(p1);     // == jnp.round
        const int c0 = (int)r0f, c1 = (int)r1f;
        const float f0 = r0f - p0, f1 = r1f - p1;
        float e0[5], e1[5];
#pragma unroll
        for (int k = 0; k < 5; ++k) {
            const float d0 = f0 + (float)(k - 2);
            const float d1 = f1 + (float)(k - 2);
            const int rr = c0 + (k - 2), cc = c1 + (k - 2);
            e0[k] = (rr >= 0 && rr < HH) ? sw * __expf(-0.5f * d0 * d0) : 0.f;
            e1[k] = (cc >= 0 && cc < WW) ? __expf(-0.5f * d1 * d1) : 0.f;
        }
#pragma unroll
        for (int a = 0; a < 5; ++a)
#pragma unroll
            for (int b = 0; b < 5; ++b) coef[a][b] = e0[a] * e1[b];
        const int a0 = min(max(c0, -2), HH + 1);
        const int a1 = min(max(c1, -2), WW + 1);
        base = ((a0 + 2) * PSTRIDE + (a1 + 2)) * 16;      // (-2,-2) corner, bytes
    }
    const int myslot = (tid / WW + 4) * PSTRIDE + (tid % WW) + 4;

    // ---- main loop over groups of 4 images ----
    int g = blockIdx.x;
    float v0 = 0.f, v1 = 0.f, v2 = 0.f, v3 = 0.f;
    if (act && g < nGroups) {
        const size_t b = (size_t)g * 4u * NPIX;
        v0 = x[b + tid];
        v1 = x[b + NPIX + tid];
        v2 = x[b + 2 * NPIX + tid];
        v3 = x[b + 3 * NPIX + tid];
    }

    float4* rw = resA;        // written this iteration
    float4* rr = resB;        // holds previous iteration's result
    bool have_prev = false;
    size_t prev_b = 0;

    for (; g < nGroups; g += gridDim.x) {
        __syncthreads();                               // A: prev taps+res writes done
        if (act) img[myslot] = make_float4(v0, v1, v2, v3);
        __syncthreads();                               // B: staging visible

        // long window: prefetch next group, drain prev result, compute
        const int gn = g + gridDim.x;
        if (act && gn < nGroups) {
            const size_t nb = (size_t)gn * 4u * NPIX;
            v0 = x[nb + tid];
            v1 = x[nb + NPIX + tid];
            v2 = x[nb + 2 * NPIX + tid];
            v3 = x[nb + 3 * NPIX + tid];
        }
        if (act && have_prev) {
            const float4 r = rr[tid];                  // un-permuted readback
            out[prev_b + tid]            = r.x;
            out[prev_b + NPIX + tid]     = r.y;
            out[prev_b + 2 * NPIX + tid] = r.z;
            out[prev_b + 3 * NPIX + tid] = r.w;
        }
        if (act) {
            float s0 = 0.f, s1 = 0.f, s2 = 0.f, s3 = 0.f;
            const char* bp = (const char*)img + base;
#pragma unroll
            for (int i = 0; i < 5; ++i)
#pragma unroll
                for (int j = 0; j < 5; ++j) {
                    const float4 v = *(const float4*)(bp + (i * PSTRIDE + j) * 16);
                    const float c = coef[i][j];
                    s0 = fmaf(c, v.x, s0);
                    s1 = fmaf(c, v.y, s1);
                    s2 = fmaf(c, v.z, s2);
                    s3 = fmaf(c, v.w, s3);
                }
            rw[ap] = make_float4(s0, s1, s2, s3);      // permuted write (1 instr)
        }
        prev_b = (size_t)g * 4u * NPIX;
        have_prev = true;
        float4* t = rw; rw = rr; rr = t;
    }

    // epilogue: flush last group's result
    __syncthreads();
    if (act && have_prev) {
        const float4 r = rr[tid];
        out[prev_b + tid]            = r.x;
        out[prev_b + NPIX + tid]     = r.y;
        out[prev_b + 2 * NPIX + tid] = r.z;
        out[prev_b + 3 * NPIX + tid] = r.w;
    }
}

extern "C" void kernel_launch(void* const* d_in, const int* in_sizes, int n_in,
                              void* d_out, int out_size, void* d_ws, size_t ws_size,
                              hipStream_t stream) {
    const float* x      = (const float*)d_in[0];   // (B,1,28,28) fp32
    const float* pos2d  = (const float*)d_in[1];   // (28,28,2)   fp32
    const float* weight = (const float*)d_in[2];   // (28,28)     fp32
    float* out = (float*)d_out;

    const int B = in_sizes[0] / NPIX;              // 32768
    const int nGroups = B / 4;                     // 8192
    int blocks = nGroups < 1024 ? nGroups : 1024;  // 2 blocks/CU resident

    hipLaunchKernelGGL(axs_89807766159734_kernel, dim3(blocks), dim3(BLOCK), 0, stream,
                       x, pos2d, weight, out, nGroups);
}

// Round 2
// 195.261 us; speedup vs baseline: 1.0318x; 1.0318x over previous
//
#include <hip/hip_runtime.h>

#define HH 28
#define WW 28
#define NPIX 784          // 28*28
#define BLOCK 832         // 13 waves; lanes 784..831 idle in compute
#define PSTRIDE 40        // padded row stride in float4 slots
#define PROWS 36          // rows -4..31 (halo 4: clamped center ±2 + taps ±2)
#define PSLOTS (PROWS * PSTRIDE)   // 1440 slots = 23040 B

// Key change this round: the 25 tap coefficients are 25 NAMED SCALARS
// (c00..c44), never an indexed array. Rounds 0/1 kept the tap table in a
// runtime-indexed array -> compiler left it in scratch (VGPR_Count=36 proved
// it), re-loading 100 B/thread from private memory every iteration.
// LDS layout: zero-padded 36x40 float4 halo tile; OOB taps read exact 0.0
// (== reference's in_b mask); every tap is ds_read_b128 [one base VGPR +
// compile-time immediate].
__global__ __launch_bounds__(BLOCK, 7) void axs_89807766159734_kernel(
    const float* __restrict__ x, const float* __restrict__ pos2d,
    const float* __restrict__ weight, float* __restrict__ out,
    int nGroups)
{
    __shared__ float4 img[PSLOTS];          // 23040 B, halo stays zero
    const int tid = threadIdx.x;
    const bool act = tid < NPIX;

    // one-time: zero the whole tile (halo persists; interior rewritten per iter)
    for (int s = tid; s < PSLOTS; s += BLOCK)
        img[s] = make_float4(0.f, 0.f, 0.f, 0.f);

    // ---- 25 coefficients as named scalars (separable: e0[i]*e1[j]) ----
    float c00=0,c01=0,c02=0,c03=0,c04=0,
          c10=0,c11=0,c12=0,c13=0,c14=0,
          c20=0,c21=0,c22=0,c23=0,c24=0,
          c30=0,c31=0,c32=0,c33=0,c34=0,
          c40=0,c41=0,c42=0,c43=0,c44=0;
    int base = 0;
    if (act) {
        const float p0 = pos2d[2 * tid], p1 = pos2d[2 * tid + 1];
        const float sw = fmaxf(weight[tid], 0.0f);        // relu(weight), folded into e0
        const float r0 = rintf(p0), r1 = rintf(p1);       // rintf == jnp.round (half-even)
        const int i0 = (int)r0, i1 = (int)r1;
        const float f0 = r0 - p0, f1 = r1 - p1;           // d = (ce+off) - pos = f + off

        const float d0m2 = f0 - 2.f, d0m1 = f0 - 1.f, d0p1 = f0 + 1.f, d0p2 = f0 + 2.f;
        const float e0m2 = (i0 - 2 >= 0 && i0 - 2 < HH) ? sw * __expf(-0.5f * d0m2 * d0m2) : 0.f;
        const float e0m1 = (i0 - 1 >= 0 && i0 - 1 < HH) ? sw * __expf(-0.5f * d0m1 * d0m1) : 0.f;
        const float e0z  = (i0     >= 0 && i0     < HH) ? sw * __expf(-0.5f * f0   * f0  ) : 0.f;
        const float e0p1 = (i0 + 1 >= 0 && i0 + 1 < HH) ? sw * __expf(-0.5f * d0p1 * d0p1) : 0.f;
        const float e0p2 = (i0 + 2 >= 0 && i0 + 2 < HH) ? sw * __expf(-0.5f * d0p2 * d0p2) : 0.f;

        const float d1m2 = f1 - 2.f, d1m1 = f1 - 1.f, d1p1 = f1 + 1.f, d1p2 = f1 + 2.f;
        const float e1m2 = (i1 - 2 >= 0 && i1 - 2 < WW) ? __expf(-0.5f * d1m2 * d1m2) : 0.f;
        const float e1m1 = (i1 - 1 >= 0 && i1 - 1 < WW) ? __expf(-0.5f * d1m1 * d1m1) : 0.f;
        const float e1z  = (i1     >= 0 && i1     < WW) ? __expf(-0.5f * f1   * f1  ) : 0.f;
        const float e1p1 = (i1 + 1 >= 0 && i1 + 1 < WW) ? __expf(-0.5f * d1p1 * d1p1) : 0.f;
        const float e1p2 = (i1 + 2 >= 0 && i1 + 2 < WW) ? __expf(-0.5f * d1p2 * d1p2) : 0.f;

        c00 = e0m2*e1m2; c01 = e0m2*e1m1; c02 = e0m2*e1z; c03 = e0m2*e1p1; c04 = e0m2*e1p2;
        c10 = e0m1*e1m2; c11 = e0m1*e1m1; c12 = e0m1*e1z; c13 = e0m1*e1p1; c14 = e0m1*e1p2;
        c20 = e0z *e1m2; c21 = e0z *e1m1; c22 = e0z *e1z; c23 = e0z *e1p1; c24 = e0z *e1p2;
        c30 = e0p1*e1m2; c31 = e0p1*e1m1; c32 = e0p1*e1z; c33 = e0p1*e1p1; c34 = e0p1*e1p2;
        c40 = e0p2*e1m2; c41 = e0p2*e1m1; c42 = e0p2*e1z; c43 = e0p2*e1p1; c44 = e0p2*e1p2;

        const int a0c = min(max(i0, -2), HH + 1);         // clamp for addressing only;
        const int a1c = min(max(i1, -2), WW + 1);         // when clamp engages, coefs are 0
        base = ((a0c + 2) * PSTRIDE + (a1c + 2)) * 16;    // (-2,-2) corner, bytes
    }
    const int myslot = (tid / WW + 4) * PSTRIDE + (tid % WW) + 4;

    // ---- main loop: groups of 4 images, double-barrier cadence ----
    int g = blockIdx.x;
    float v0 = 0.f, v1 = 0.f, v2 = 0.f, v3 = 0.f;
    if (act && g < nGroups) {
        const size_t b = (size_t)g * 4u * NPIX;
        v0 = x[b + tid];
        v1 = x[b + NPIX + tid];
        v2 = x[b + 2 * NPIX + tid];
        v3 = x[b + 3 * NPIX + tid];
    }

    for (; g < nGroups; g += gridDim.x) {
        __syncthreads();                               // prev compute done (and init)
        if (act) img[myslot] = make_float4(v0, v1, v2, v3);   // ds_write_b128
        __syncthreads();                               // staging visible

        // prefetch next group's 4 floats while computing from LDS
        const int gn = g + gridDim.x;
        if (act && gn < nGroups) {
            const size_t nb = (size_t)gn * 4u * NPIX;
            v0 = x[nb + tid];
            v1 = x[nb + NPIX + tid];
            v2 = x[nb + 2 * NPIX + tid];
            v3 = x[nb + 3 * NPIX + tid];
        }

        if (act) {
            float a0 = 0.f, a1 = 0.f, a2 = 0.f, a3 = 0.f;
            const char* bp = (const char*)img + base;
#define TAP(I, J, C) do {                                                  \
            const float4 tv = *(const float4*)(bp + ((I) * PSTRIDE + (J)) * 16); \
            a0 = fmaf(C, tv.x, a0); a1 = fmaf(C, tv.y, a1);                \
            a2 = fmaf(C, tv.z, a2); a3 = fmaf(C, tv.w, a3); } while (0)
            TAP(0,0,c00); TAP(0,1,c01); TAP(0,2,c02); TAP(0,3,c03); TAP(0,4,c04);
            TAP(1,0,c10); TAP(1,1,c11); TAP(1,2,c12); TAP(1,3,c13); TAP(1,4,c14);
            TAP(2,0,c20); TAP(2,1,c21); TAP(2,2,c22); TAP(2,3,c23); TAP(2,4,c24);
            TAP(3,0,c30); TAP(3,1,c31); TAP(3,2,c32); TAP(3,3,c33); TAP(3,4,c34);
            TAP(4,0,c40); TAP(4,1,c41); TAP(4,2,c42); TAP(4,3,c43); TAP(4,4,c44);
#undef TAP
            const size_t b = (size_t)g * 4u * NPIX;
            out[b + tid]            = a0;
            out[b + NPIX + tid]     = a1;
            out[b + 2 * NPIX + tid] = a2;
            out[b + 3 * NPIX + tid] = a3;
        }
    }
}

extern "C" void kernel_launch(void* const* d_in, const int* in_sizes, int n_in,
                              void* d_out, int out_size, void* d_ws, size_t ws_size,
                              hipStream_t stream) {
    const float* x      = (const float*)d_in[0];   // (B,1,28,28) fp32
    const float* pos2d  = (const float*)d_in[1];   // (28,28,2)   fp32
    const float* weight = (const float*)d_in[2];   // (28,28)     fp32
    float* out = (float*)d_out;

    const int B = in_sizes[0] / NPIX;              // 32768
    const int nGroups = B / 4;                     // 8192
    int blocks = nGroups < 1024 ? nGroups : 1024;  // 2 blocks/CU resident (26 waves)

    hipLaunchKernelGGL(axs_89807766159734_kernel, dim3(blocks), dim3(BLOCK), 0, stream,
                       x, pos2d, weight, out, nGroups);
}

// Round 3
// 185.244 us; speedup vs baseline: 1.0876x; 1.0541x over previous
//
#include <hip/hip_runtime.h>
#include <hip/hip_fp16.h>

#define HH 28
#define WW 28
#define NPIX 784          // 28*28
#define BLOCK 832         // 13 waves; lanes 784..831 idle in compute
#define PSTRIDE 44        // slots/row: 44 = 12 (mod 16), wrap 44-27=17 = +1 (mod 16)
                          // -> LDS slot residue advances +1 per pixel: gather base
                          //    pattern is conflict-free for any phase grouping.
#define PROWS 36          // rows -4..31 (clamped center +-2 plus taps +-2)
#define PSLOTS (PROWS * PSTRIDE)   // 1584 slots * 16 B = 25344 B

// Round-3 change: LDS pipe is ~97% busy (25 b128 per 4 outputs = the whole
// runtime). Stage 8 IMAGES AS PACKED FP16 per pixel (uint4 = 4x half2), so one
// ds_read_b128 feeds 8 outputs -> LDS cycles per output halve. fp16-RN input
// error (<=2.7e-3 * coef<=0.217) stays well inside the 2^-7 tolerance.
// Coefficients remain 25 named scalars; taps are base-VGPR + compile-time
// immediates into a zero-padded halo tile (OOB reads exact 0.0 == in_b mask).
__global__ __launch_bounds__(BLOCK, 7) void axs_89807766159734_kernel(
    const float* __restrict__ x, const float* __restrict__ pos2d,
    const float* __restrict__ weight, float* __restrict__ out,
    int nGroups)
{
    __shared__ uint4 img[PSLOTS];          // 25344 B, halo stays zero
    const int tid = threadIdx.x;
    const bool act = tid < NPIX;

    // one-time: zero the tile (halo persists; interior rewritten every iter)
    for (int s = tid; s < PSLOTS; s += BLOCK)
        img[s] = make_uint4(0u, 0u, 0u, 0u);

    // ---- 25 coefficients as named scalars (separable: e0[i]*e1[j]) ----
    float c00=0,c01=0,c02=0,c03=0,c04=0,
          c10=0,c11=0,c12=0,c13=0,c14=0,
          c20=0,c21=0,c22=0,c23=0,c24=0,
          c30=0,c31=0,c32=0,c33=0,c34=0,
          c40=0,c41=0,c42=0,c43=0,c44=0;
    int base = 0;
    if (act) {
        const float p0 = pos2d[2 * tid], p1 = pos2d[2 * tid + 1];
        const float sw = fmaxf(weight[tid], 0.0f);        // relu(weight) folded in
        const float r0 = rintf(p0), r1 = rintf(p1);       // rintf == jnp.round
        const int i0 = (int)r0, i1 = (int)r1;
        const float f0 = r0 - p0, f1 = r1 - p1;           // d = f + off

        const float d0m2 = f0 - 2.f, d0m1 = f0 - 1.f, d0p1 = f0 + 1.f, d0p2 = f0 + 2.f;
        const float e0m2 = (i0 - 2 >= 0 && i0 - 2 < HH) ? sw * __expf(-0.5f * d0m2 * d0m2) : 0.f;
        const float e0m1 = (i0 - 1 >= 0 && i0 - 1 < HH) ? sw * __expf(-0.5f * d0m1 * d0m1) : 0.f;
        const float e0z  = (i0     >= 0 && i0     < HH) ? sw * __expf(-0.5f * f0   * f0  ) : 0.f;
        const float e0p1 = (i0 + 1 >= 0 && i0 + 1 < HH) ? sw * __expf(-0.5f * d0p1 * d0p1) : 0.f;
        const float e0p2 = (i0 + 2 >= 0 && i0 + 2 < HH) ? sw * __expf(-0.5f * d0p2 * d0p2) : 0.f;

        const float d1m2 = f1 - 2.f, d1m1 = f1 - 1.f, d1p1 = f1 + 1.f, d1p2 = f1 + 2.f;
        const float e1m2 = (i1 - 2 >= 0 && i1 - 2 < WW) ? __expf(-0.5f * d1m2 * d1m2) : 0.f;
        const float e1m1 = (i1 - 1 >= 0 && i1 - 1 < WW) ? __expf(-0.5f * d1m1 * d1m1) : 0.f;
        const float e1z  = (i1     >= 0 && i1     < WW) ? __expf(-0.5f * f1   * f1  ) : 0.f;
        const float e1p1 = (i1 + 1 >= 0 && i1 + 1 < WW) ? __expf(-0.5f * d1p1 * d1p1) : 0.f;
        const float e1p2 = (i1 + 2 >= 0 && i1 + 2 < WW) ? __expf(-0.5f * d1p2 * d1p2) : 0.f;

        c00 = e0m2*e1m2; c01 = e0m2*e1m1; c02 = e0m2*e1z; c03 = e0m2*e1p1; c04 = e0m2*e1p2;
        c10 = e0m1*e1m2; c11 = e0m1*e1m1; c12 = e0m1*e1z; c13 = e0m1*e1p1; c14 = e0m1*e1p2;
        c20 = e0z *e1m2; c21 = e0z *e1m1; c22 = e0z *e1z; c23 = e0z *e1p1; c24 = e0z *e1p2;
        c30 = e0p1*e1m2; c31 = e0p1*e1m1; c32 = e0p1*e1z; c33 = e0p1*e1p1; c34 = e0p1*e1p2;
        c40 = e0p2*e1m2; c41 = e0p2*e1m1; c42 = e0p2*e1z; c43 = e0p2*e1p1; c44 = e0p2*e1p2;

        const int a0c = min(max(i0, -2), HH + 1);         // addressing clamp only;
        const int a1c = min(max(i1, -2), WW + 1);         // clamped => coefs all 0
        base = ((a0c + 2) * PSTRIDE + (a1c + 2)) * 16;    // (-2,-2) corner, bytes
    }
    const int myslot = (tid / WW + 4) * PSTRIDE + (tid % WW) + 4;

    // ---- main loop: groups of 8 images ----
    int g = blockIdx.x;
    float v0=0,v1=0,v2=0,v3=0,v4=0,v5=0,v6=0,v7=0;
    if (act && g < nGroups) {
        const size_t b = (size_t)g * 8u * NPIX;
        v0 = x[b + tid];            v1 = x[b + NPIX + tid];
        v2 = x[b + 2*NPIX + tid];   v3 = x[b + 3*NPIX + tid];
        v4 = x[b + 4*NPIX + tid];   v5 = x[b + 5*NPIX + tid];
        v6 = x[b + 6*NPIX + tid];   v7 = x[b + 7*NPIX + tid];
    }

    for (; g < nGroups; g += gridDim.x) {
        __syncthreads();                               // prev compute done (and init)
        if (act) {
            uint4 pk;
            pk.x = __builtin_bit_cast(unsigned int, __floats2half2_rn(v0, v1));
            pk.y = __builtin_bit_cast(unsigned int, __floats2half2_rn(v2, v3));
            pk.z = __builtin_bit_cast(unsigned int, __floats2half2_rn(v4, v5));
            pk.w = __builtin_bit_cast(unsigned int, __floats2half2_rn(v6, v7));
            img[myslot] = pk;                          // ds_write_b128
        }
        __syncthreads();                               // staging visible

        // prefetch next group's 8 floats while computing from LDS
        const int gn = g + gridDim.x;
        if (act && gn < nGroups) {
            const size_t nb = (size_t)gn * 8u * NPIX;
            v0 = x[nb + tid];            v1 = x[nb + NPIX + tid];
            v2 = x[nb + 2*NPIX + tid];   v3 = x[nb + 3*NPIX + tid];
            v4 = x[nb + 4*NPIX + tid];   v5 = x[nb + 5*NPIX + tid];
            v6 = x[nb + 6*NPIX + tid];   v7 = x[nb + 7*NPIX + tid];
        }

        if (act) {
            float a0=0,a1=0,a2=0,a3=0,a4=0,a5=0,a6=0,a7=0;
            const char* bp = (const char*)img + base;
#define TAP(I, J, C) do {                                                    \
            const uint4 tv = *(const uint4*)(bp + ((I) * PSTRIDE + (J)) * 16); \
            const __half2 q0 = __builtin_bit_cast(__half2, tv.x);            \
            const __half2 q1 = __builtin_bit_cast(__half2, tv.y);            \
            const __half2 q2 = __builtin_bit_cast(__half2, tv.z);            \
            const __half2 q3 = __builtin_bit_cast(__half2, tv.w);            \
            a0 = fmaf(C, __low2float(q0), a0);  a1 = fmaf(C, __high2float(q0), a1); \
            a2 = fmaf(C, __low2float(q1), a2);  a3 = fmaf(C, __high2float(q1), a3); \
            a4 = fmaf(C, __low2float(q2), a4);  a5 = fmaf(C, __high2float(q2), a5); \
            a6 = fmaf(C, __low2float(q3), a6);  a7 = fmaf(C, __high2float(q3), a7); \
        } while (0)
            TAP(0,0,c00); TAP(0,1,c01); TAP(0,2,c02); TAP(0,3,c03); TAP(0,4,c04);
            TAP(1,0,c10); TAP(1,1,c11); TAP(1,2,c12); TAP(1,3,c13); TAP(1,4,c14);
            TAP(2,0,c20); TAP(2,1,c21); TAP(2,2,c22); TAP(2,3,c23); TAP(2,4,c24);
            TAP(3,0,c30); TAP(3,1,c31); TAP(3,2,c32); TAP(3,3,c33); TAP(3,4,c34);
            TAP(4,0,c40); TAP(4,1,c41); TAP(4,2,c42); TAP(4,3,c43); TAP(4,4,c44);
#undef TAP
            const size_t b = (size_t)g * 8u * NPIX;
            out[b + tid]          = a0;  out[b + NPIX + tid]   = a1;
            out[b + 2*NPIX + tid] = a2;  out[b + 3*NPIX + tid] = a3;
            out[b + 4*NPIX + tid] = a4;  out[b + 5*NPIX + tid] = a5;
            out[b + 6*NPIX + tid] = a6;  out[b + 7*NPIX + tid] = a7;
        }
    }
}

extern "C" void kernel_launch(void* const* d_in, const int* in_sizes, int n_in,
                              void* d_out, int out_size, void* d_ws, size_t ws_size,
                              hipStream_t stream) {
    const float* x      = (const float*)d_in[0];   // (B,1,28,28) fp32
    const float* pos2d  = (const float*)d_in[1];   // (28,28,2)   fp32
    const float* weight = (const float*)d_in[2];   // (28,28)     fp32
    float* out = (float*)d_out;

    const int B = in_sizes[0] / NPIX;              // 32768
    const int nGroups = B / 8;                     // 4096
    int blocks = nGroups < 1024 ? nGroups : 1024;  // 2 blocks/CU resident (26 waves)

    hipLaunchKernelGGL(axs_89807766159734_kernel, dim3(blocks), dim3(BLOCK), 0, stream,
                       x, pos2d, weight, out, nGroups);
}